// Round 6
// baseline (114.370 us; speedup 1.0000x reference)
//
#include <hip/hip_runtime.h>
#include <hip/hip_bf16.h>
#include <math.h>

// Problem constants: B=256, V=2048, PD=1024, MD=512, H=512
typedef __attribute__((ext_vector_type(8))) short short8;
typedef __attribute__((ext_vector_type(4))) float float4v;
typedef __attribute__((ext_vector_type(2))) float float2v;

// SSA-safe half extraction (NO unions -- unions block SROA and spill).
__device__ __forceinline__ float2v lo2(float4v v) {
    return __builtin_shufflevector(v, v, 0, 1);
}
__device__ __forceinline__ float2v hi2(float4v v) {
    return __builtin_shufflevector(v, v, 2, 3);
}

__device__ __forceinline__ int2 cvt2bf16x4(float4v v) {
    union { __hip_bfloat162 h2; int i; } u0, u1;
    u0.h2 = __float22bfloat162_rn(make_float2(v.x, v.y));  // v_cvt_pk_bf16_f32
    u1.h2 = __float22bfloat162_rn(make_float2(v.z, v.w));
    return make_int2(u0.i, u1.i);
}

// Fused dual GEMM + exp epilogue (plain [h][x] layout, contiguous stores).
//  bx 0..3:  EA[h][b] = exp(2*(patient@W1p^T + b1))   M=256,  K=1024
//  bx 4..35: EM[h][v] = exp(2*(atc4@W1m^T))           M=2048, K=512
// Round 6: __launch_bounds__(256, 2) -- default heuristic capped VGPR at the
// 8-waves/EU boundary (64), forcing the 32-reg k-tile prefetch + 16 acc +
// fragments to spill/remat every k-iter. Cap 256 VGPR (2 blocks/CU target;
// grid is 1.125 blocks/CU anyway).
// NOTE (round-3 lesson): do NOT fuse cross-block reductions with
// __threadfence on this chip -- agent-scope fences flush per-XCD L2 and
// cost ~30 us. Separate dispatches keep workspace traffic L2-hot.
__global__ __launch_bounds__(256, 2) void gemm_exp(
    const float* __restrict__ patient, const float* __restrict__ atc4,
    const float* __restrict__ W1, const float* __restrict__ b1,
    float* __restrict__ EA, float* __restrict__ EM)
{
    const float* A; const float* W; const float* bias; float* T;
    int lda, K, M;
    int bx = blockIdx.x;
    if (bx < 4) {
        A = patient; lda = 1024; K = 1024; M = 256; bias = b1; T = EA; W = W1;
    } else {
        bx -= 4;
        A = atc4;    lda = 512;  K = 512;  M = 2048; bias = nullptr; T = EM; W = W1 + 1024;
    }
    const int ldw = 1536;

    __shared__ short As[64][72];
    __shared__ short Bs[64][72];
    const int t = threadIdx.x;
    const int m0 = bx * 64;
    const int n0 = blockIdx.y * 64;
    const int wave = t >> 6;
    const int lane = t & 63;
    const int wm = (wave & 1) * 32;
    const int wn = (wave >> 1) * 32;
    const int lrow = lane & 15;
    const int quad = lane >> 4;

    float4v acc[2][2];
    #pragma unroll
    for (int i = 0; i < 2; i++)
        #pragma unroll
        for (int j = 0; j < 2; j++)
            acc[i][j] = (float4v){0.f, 0.f, 0.f, 0.f};

    const int sr = t >> 2;        // staging row 0..63
    const int sc = (t & 3) * 16;  // staging col 0,16,32,48

    // preload k-tile 0 into registers
    float4v av[4], wv[4];
    {
        const float* ap = A + (size_t)(m0 + sr) * lda + sc;
        const float* wp = W + (size_t)(n0 + sr) * ldw + sc;
        #pragma unroll
        for (int ii = 0; ii < 4; ii++) {
            av[ii] = *(const float4v*)(ap + ii * 4);
            wv[ii] = *(const float4v*)(wp + ii * 4);
        }
    }

    for (int k0 = 0; k0 < K; k0 += 64) {
        #pragma unroll
        for (int ii = 0; ii < 4; ii++) {
            *(int2*)&As[sr][sc + ii * 4] = cvt2bf16x4(av[ii]);
            *(int2*)&Bs[sr][sc + ii * 4] = cvt2bf16x4(wv[ii]);
        }
        __syncthreads();
        if (k0 + 64 < K) {   // prefetch next k-tile; latency hides under MFMA
            const float* ap = A + (size_t)(m0 + sr) * lda + (k0 + 64 + sc);
            const float* wp = W + (size_t)(n0 + sr) * ldw + (k0 + 64 + sc);
            #pragma unroll
            for (int ii = 0; ii < 4; ii++) {
                av[ii] = *(const float4v*)(ap + ii * 4);
                wv[ii] = *(const float4v*)(wp + ii * 4);
            }
        }
        #pragma unroll
        for (int kk = 0; kk < 64; kk += 32) {
            short8 af[2], bfr[2];
            #pragma unroll
            for (int i = 0; i < 2; i++)
                af[i] = *(const short8*)&As[wm + i * 16 + lrow][kk + quad * 8];
            #pragma unroll
            for (int j = 0; j < 2; j++)
                bfr[j] = *(const short8*)&Bs[wn + j * 16 + lrow][kk + quad * 8];
            #pragma unroll
            for (int i = 0; i < 2; i++)
                #pragma unroll
                for (int j = 0; j < 2; j++)
                    acc[i][j] = __builtin_amdgcn_mfma_f32_16x16x32_bf16(
                        af[i], bfr[j], acc[i][j], 0, 0, 0);
        }
        __syncthreads();
    }

    // D layout (verified m89/m91): col(n)=lane&15, row(m)=quad*4+reg
    #pragma unroll
    for (int i = 0; i < 2; i++) {
        #pragma unroll
        for (int j = 0; j < 2; j++) {
            const int n  = n0 + wn + j * 16 + lrow;
            const int mb = m0 + wm + i * 16 + quad * 4;
            const float bn = bias ? bias[n] : 0.0f;
            float4v ev;
            #pragma unroll
            for (int r = 0; r < 4; r++)
                ev[r] = __expf(2.0f * (acc[i][j][r] + bn));
            *(float4v*)&T[(size_t)n * M + mb] = ev;
        }
    }
}

// 4-h rational block: acc += sum_{k=0..3} c_k / d_k, d_k = 1 + em_k*a_k.
//   (n01*e23 + n23*e01)/(e01*e23); all d >= 1 so no cancellation.
__device__ __forceinline__ void rat4(
    float2v em0, float2v em1, float2v em2, float2v em3,
    float2v a0, float2v a1, float2v a2, float2v a3,
    float2v c0, float2v c1, float2v c2, float2v c3,
    float2v& acc)
{
    const float2v one2 = {1.f, 1.f};
    float2v d0 = __builtin_elementwise_fma(em0, a0, one2);
    float2v d1 = __builtin_elementwise_fma(em1, a1, one2);
    float2v d2 = __builtin_elementwise_fma(em2, a2, one2);
    float2v d3 = __builtin_elementwise_fma(em3, a3, one2);
    float2v e01 = d0 * d1;
    float2v e23 = d2 * d3;
    float2v n01 = __builtin_elementwise_fma(d1, c0, d0 * c1);
    float2v n23 = __builtin_elementwise_fma(d3, c2, d2 * c3);
    float2v num = __builtin_elementwise_fma(n01, e23, n23 * e01);
    float2v den = e01 * e23;
    float2v r = { __builtin_amdgcn_rcpf(den.x), __builtin_amdgcn_rcpf(den.y) };
    acc = __builtin_elementwise_fma(num, r, acc);
}

// partial[z][b][v] = sum_{h in 32-chunk z} [ w2[h] + c_h / d_h ],
//   c = -2*w2, d = 1 + Ea[h][b]*Em[h][v]    (w2*tanh(x) = w2 - 2*w2/(1+e^{2x}))
// Round 6: __launch_bounds__(256, 4). Rounds 0-5 showed pair stuck at
// ~38-47 us regardless of occupancy (1/2/4/8 blocks/CU) and LDS bytes/term
// -- the signature of a per-CU shared-resource bound. VGPR_Count was
// exactly 64 (the 8-waves/EU allocator boundary) while the live set
// (32 acc + 16 em halves + splats + addrs) is ~100: the allocator kept
// pressure at 64 by re-reading em fragments from LDS inside the i-loop,
// saturating the CU's LDS issue pipe. Cap 128 VGPR (4 blocks/CU target,
// matching the (16,4,16) grid) so the fragments stay live.
__global__ __launch_bounds__(256, 4) void pair_kernel(
    const float* __restrict__ EA, const float* __restrict__ EM,
    const float* __restrict__ w2, float* __restrict__ partial)
{
    __shared__ float sEA[32][68];    // [h][b], 64 cols used
    __shared__ float sEM[32][132];   // [h][v], 128 cols used
    __shared__ float4v sC4[8];       // -2*w2 quads for the 32-h chunk
    const int t  = threadIdx.x;
    const int v0 = blockIdx.x * 128;
    const int b0 = blockIdx.y * 64;
    const int h0 = blockIdx.z * 32;
    const int tx = t & 15;   // quad A: v = v0 + tx*4 + j ; quad B: +64
    const int ty = t >> 4;   // b = b0 + ty*4 + i

    if (t < 8) {
        float4v wvq = *(const float4v*)(w2 + h0 + 4 * t);
        sC4[t] = -2.0f * wvq;
    }

    float2v accAL[4], accAH[4], accBL[4], accBH[4];
    #pragma unroll
    for (int i = 0; i < 4; i++) {
        accAL[i] = (float2v){0.f, 0.f};  accAH[i] = (float2v){0.f, 0.f};
        accBL[i] = (float2v){0.f, 0.f};  accBH[i] = (float2v){0.f, 0.f};
    }

    const int rS = t >> 3;          // staging row 0..31
    const int cA = (t & 7) * 8;     // EA cols (64/row, 2 float4)
    const int cM = (t & 7) * 16;    // EM cols (128/row, 4 float4)

    // ---- stage the block's 32-h chunk (once) ----
    {
        const float* pa = EA + (size_t)(h0 + rS) * 256 + b0 + cA;
        float4v pA0 = *(const float4v*)pa;
        float4v pA1 = *(const float4v*)(pa + 4);
        const float* pm = EM + (size_t)(h0 + rS) * 2048 + v0 + cM;
        float4v pM0 = *(const float4v*)pm;
        float4v pM1 = *(const float4v*)(pm + 4);
        float4v pM2 = *(const float4v*)(pm + 8);
        float4v pM3 = *(const float4v*)(pm + 12);
        *(float4v*)&sEA[rS][cA] = pA0;      *(float4v*)&sEA[rS][cA + 4] = pA1;
        *(float4v*)&sEM[rS][cM] = pM0;      *(float4v*)&sEM[rS][cM + 4] = pM1;
        *(float4v*)&sEM[rS][cM + 8] = pM2;  *(float4v*)&sEM[rS][cM + 12] = pM3;
    }
    __syncthreads();

    #pragma unroll 2
    for (int q = 0; q < 8; q++) {           // 4 h per iteration
        const int hq = 4 * q;
        // ea: 4 b-values per h row (broadcast within 16-lane groups)
        const float4v ea0 = *(const float4v*)&sEA[hq    ][ty * 4];
        const float4v ea1 = *(const float4v*)&sEA[hq + 1][ty * 4];
        const float4v ea2 = *(const float4v*)&sEA[hq + 2][ty * 4];
        const float4v ea3 = *(const float4v*)&sEA[hq + 3][ty * 4];
        const float4v c = sC4[q];
        const float2v c0 = { c.x, c.x };
        const float2v c1 = { c.y, c.y };
        const float2v c2 = { c.z, c.z };
        const float2v c3 = { c.w, c.w };
        // ---- quad A (v = v0 + tx*4) ----
        {
            const float4v em0 = *(const float4v*)&sEM[hq    ][tx * 4];
            const float4v em1 = *(const float4v*)&sEM[hq + 1][tx * 4];
            const float4v em2 = *(const float4v*)&sEM[hq + 2][tx * 4];
            const float4v em3 = *(const float4v*)&sEM[hq + 3][tx * 4];
            const float2v em0L = lo2(em0), em0H = hi2(em0);
            const float2v em1L = lo2(em1), em1H = hi2(em1);
            const float2v em2L = lo2(em2), em2H = hi2(em2);
            const float2v em3L = lo2(em3), em3H = hi2(em3);
            #pragma unroll
            for (int i = 0; i < 4; i++) {
                const float2v a0 = { ea0[i], ea0[i] };
                const float2v a1 = { ea1[i], ea1[i] };
                const float2v a2 = { ea2[i], ea2[i] };
                const float2v a3 = { ea3[i], ea3[i] };
                rat4(em0L, em1L, em2L, em3L, a0, a1, a2, a3,
                     c0, c1, c2, c3, accAL[i]);
                rat4(em0H, em1H, em2H, em3H, a0, a1, a2, a3,
                     c0, c1, c2, c3, accAH[i]);
            }
        }
        // ---- quad B (v = v0 + 64 + tx*4) ----
        {
            const float4v em0 = *(const float4v*)&sEM[hq    ][64 + tx * 4];
            const float4v em1 = *(const float4v*)&sEM[hq + 1][64 + tx * 4];
            const float4v em2 = *(const float4v*)&sEM[hq + 2][64 + tx * 4];
            const float4v em3 = *(const float4v*)&sEM[hq + 3][64 + tx * 4];
            const float2v em0L = lo2(em0), em0H = hi2(em0);
            const float2v em1L = lo2(em1), em1H = hi2(em1);
            const float2v em2L = lo2(em2), em2H = hi2(em2);
            const float2v em3L = lo2(em3), em3H = hi2(em3);
            #pragma unroll
            for (int i = 0; i < 4; i++) {
                const float2v a0 = { ea0[i], ea0[i] };
                const float2v a1 = { ea1[i], ea1[i] };
                const float2v a2 = { ea2[i], ea2[i] };
                const float2v a3 = { ea3[i], ea3[i] };
                rat4(em0L, em1L, em2L, em3L, a0, a1, a2, a3,
                     c0, c1, c2, c3, accBL[i]);
                rat4(em0H, em1H, em2H, em3H, a0, a1, a2, a3,
                     c0, c1, c2, c3, accBH[i]);
            }
        }
    }

    // chunk's sum(w2) from sC4 (sC4 = -2*w2)
    float4v w2q = sC4[0];
    #pragma unroll
    for (int k = 1; k < 8; k++) w2q += sC4[k];
    const float w2s = -0.5f * (w2q.x + w2q.y + w2q.z + w2q.w);

    const size_t pb = (size_t)blockIdx.z * (256 * 2048);
    #pragma unroll
    for (int i = 0; i < 4; i++) {
        const size_t row = pb + (size_t)(b0 + ty * 4 + i) * 2048 + v0 + tx * 4;
        float4v oA = { accAL[i].x + w2s, accAL[i].y + w2s,
                       accAH[i].x + w2s, accAH[i].y + w2s };
        float4v oB = { accBL[i].x + w2s, accBL[i].y + w2s,
                       accBH[i].x + w2s, accBH[i].y + w2s };
        *(float4v*)&partial[row] = oA;
        *(float4v*)&partial[row + 64] = oB;
    }
}

__global__ __launch_bounds__(256) void reduce_kernel(
    const float* __restrict__ partial, const float* __restrict__ b2,
    float* __restrict__ out)
{
    const int i = (blockIdx.x * 256 + threadIdx.x) * 4;
    const float bb = b2[0];
    float4v s = *(const float4v*)&partial[i];
    #pragma unroll
    for (int z = 1; z < 16; z++)
        s += *(const float4v*)&partial[(size_t)z * 524288 + i];
    float4v o = s + bb;
    *(float4v*)&out[i] = o;
}

extern "C" void kernel_launch(void* const* d_in, const int* in_sizes, int n_in,
                              void* d_out, int out_size, void* d_ws, size_t ws_size,
                              hipStream_t stream)
{
    const float* patient = (const float*)d_in[0]; // 256x1024
    const float* atc4    = (const float*)d_in[1]; // 2048x512
    const float* W1      = (const float*)d_in[2]; // 512x1536
    const float* b1      = (const float*)d_in[3]; // 512
    const float* w2      = (const float*)d_in[4]; // 512
    const float* b2      = (const float*)d_in[5]; // 1
    float* out = (float*)d_out;
    float* ws  = (float*)d_ws;

    // ws layout (floats): EA[512][256], EM[512][2048],
    //                     partial[16][256][2048] => ~38 MB
    float* EA      = ws;
    float* EM      = ws + 131072;
    float* partial = ws + 1179648;

    // Both GEMMs in one dispatch (compacted grid, EA tiles first); exp(2x) epilogue
    gemm_exp<<<dim3(36, 8, 1), 256, 0, stream>>>(patient, atc4, W1, b1, EA, EM);
    // score partials: single-stage 32-h blocks, 4 blocks/CU, 128-VGPR cap
    pair_kernel<<<dim3(16, 4, 16), 256, 0, stream>>>(EA, EM, w2, partial);
    // sum 16 h-chunks + b2
    reduce_kernel<<<512, 256, 0, stream>>>(partial, b2, out);
}

// Round 7
// 113.046 us; speedup vs baseline: 1.0117x; 1.0117x over previous
//
#include <hip/hip_runtime.h>
#include <hip/hip_bf16.h>
#include <math.h>

// Problem constants: B=256, V=2048, PD=1024, MD=512, H=512
typedef __attribute__((ext_vector_type(8))) short short8;
typedef __attribute__((ext_vector_type(4))) float float4v;
typedef __attribute__((ext_vector_type(2))) float float2v;

// SSA-safe half extraction (NO unions -- unions block SROA and spill).
__device__ __forceinline__ float2v lo2(float4v v) {
    return __builtin_shufflevector(v, v, 0, 1);
}
__device__ __forceinline__ float2v hi2(float4v v) {
    return __builtin_shufflevector(v, v, 2, 3);
}

__device__ __forceinline__ int2 cvt2bf16x4(float4v v) {
    union { __hip_bfloat162 h2; int i; } u0, u1;
    u0.h2 = __float22bfloat162_rn(make_float2(v.x, v.y));  // v_cvt_pk_bf16_f32
    u1.h2 = __float22bfloat162_rn(make_float2(v.z, v.w));
    return make_int2(u0.i, u1.i);
}

// Fused dual GEMM + exp epilogue (plain [h][x] layout, contiguous stores).
//  bx 0..3:  EA[h][b] = exp(2*(patient@W1p^T + b1))   M=256,  K=1024
//  bx 4..35: EM[h][v] = exp(2*(atc4@W1m^T))           M=2048, K=512
// NOTE (round-3 lesson): do NOT fuse cross-block reductions with
// __threadfence on this chip -- agent-scope fences flush per-XCD L2 and
// cost ~30 us. Separate dispatches keep workspace traffic L2-hot.
__global__ __launch_bounds__(256, 2) void gemm_exp(
    const float* __restrict__ patient, const float* __restrict__ atc4,
    const float* __restrict__ W1, const float* __restrict__ b1,
    float* __restrict__ EA, float* __restrict__ EM)
{
    const float* A; const float* W; const float* bias; float* T;
    int lda, K, M;
    int bx = blockIdx.x;
    if (bx < 4) {
        A = patient; lda = 1024; K = 1024; M = 256; bias = b1; T = EA; W = W1;
    } else {
        bx -= 4;
        A = atc4;    lda = 512;  K = 512;  M = 2048; bias = nullptr; T = EM; W = W1 + 1024;
    }
    const int ldw = 1536;

    __shared__ short As[64][72];
    __shared__ short Bs[64][72];
    const int t = threadIdx.x;
    const int m0 = bx * 64;
    const int n0 = blockIdx.y * 64;
    const int wave = t >> 6;
    const int lane = t & 63;
    const int wm = (wave & 1) * 32;
    const int wn = (wave >> 1) * 32;
    const int lrow = lane & 15;
    const int quad = lane >> 4;

    float4v acc[2][2];
    #pragma unroll
    for (int i = 0; i < 2; i++)
        #pragma unroll
        for (int j = 0; j < 2; j++)
            acc[i][j] = (float4v){0.f, 0.f, 0.f, 0.f};

    const int sr = t >> 2;        // staging row 0..63
    const int sc = (t & 3) * 16;  // staging col 0,16,32,48

    // preload k-tile 0 into registers
    float4v av[4], wv[4];
    {
        const float* ap = A + (size_t)(m0 + sr) * lda + sc;
        const float* wp = W + (size_t)(n0 + sr) * ldw + sc;
        #pragma unroll
        for (int ii = 0; ii < 4; ii++) {
            av[ii] = *(const float4v*)(ap + ii * 4);
            wv[ii] = *(const float4v*)(wp + ii * 4);
        }
    }

    for (int k0 = 0; k0 < K; k0 += 64) {
        #pragma unroll
        for (int ii = 0; ii < 4; ii++) {
            *(int2*)&As[sr][sc + ii * 4] = cvt2bf16x4(av[ii]);
            *(int2*)&Bs[sr][sc + ii * 4] = cvt2bf16x4(wv[ii]);
        }
        __syncthreads();
        if (k0 + 64 < K) {   // prefetch next k-tile; latency hides under MFMA
            const float* ap = A + (size_t)(m0 + sr) * lda + (k0 + 64 + sc);
            const float* wp = W + (size_t)(n0 + sr) * ldw + (k0 + 64 + sc);
            #pragma unroll
            for (int ii = 0; ii < 4; ii++) {
                av[ii] = *(const float4v*)(ap + ii * 4);
                wv[ii] = *(const float4v*)(wp + ii * 4);
            }
        }
        #pragma unroll
        for (int kk = 0; kk < 64; kk += 32) {
            short8 af[2], bfr[2];
            #pragma unroll
            for (int i = 0; i < 2; i++)
                af[i] = *(const short8*)&As[wm + i * 16 + lrow][kk + quad * 8];
            #pragma unroll
            for (int j = 0; j < 2; j++)
                bfr[j] = *(const short8*)&Bs[wn + j * 16 + lrow][kk + quad * 8];
            #pragma unroll
            for (int i = 0; i < 2; i++)
                #pragma unroll
                for (int j = 0; j < 2; j++)
                    acc[i][j] = __builtin_amdgcn_mfma_f32_16x16x32_bf16(
                        af[i], bfr[j], acc[i][j], 0, 0, 0);
        }
        __syncthreads();
    }

    // D layout (verified m89/m91): col(n)=lane&15, row(m)=quad*4+reg
    #pragma unroll
    for (int i = 0; i < 2; i++) {
        #pragma unroll
        for (int j = 0; j < 2; j++) {
            const int n  = n0 + wn + j * 16 + lrow;
            const int mb = m0 + wm + i * 16 + quad * 4;
            const float bn = bias ? bias[n] : 0.0f;
            float4v ev;
            #pragma unroll
            for (int r = 0; r < 4; r++)
                ev[r] = __expf(2.0f * (acc[i][j][r] + bn));
            *(float4v*)&T[(size_t)n * M + mb] = ev;
        }
    }
}

// 4-h rational block: acc += sum_{k=0..3} c_k / d_k, d_k = 1 + em_k*a_k.
//   (n01*e23 + n23*e01)/(e01*e23); all d >= 1 so no cancellation.
__device__ __forceinline__ void rat4(
    float2v em0, float2v em1, float2v em2, float2v em3,
    float2v a0, float2v a1, float2v a2, float2v a3,
    float2v c0, float2v c1, float2v c2, float2v c3,
    float2v& acc)
{
    const float2v one2 = {1.f, 1.f};
    float2v d0 = __builtin_elementwise_fma(em0, a0, one2);
    float2v d1 = __builtin_elementwise_fma(em1, a1, one2);
    float2v d2 = __builtin_elementwise_fma(em2, a2, one2);
    float2v d3 = __builtin_elementwise_fma(em3, a3, one2);
    float2v e01 = d0 * d1;
    float2v e23 = d2 * d3;
    float2v n01 = __builtin_elementwise_fma(d1, c0, d0 * c1);
    float2v n23 = __builtin_elementwise_fma(d3, c2, d2 * c3);
    float2v num = __builtin_elementwise_fma(n01, e23, n23 * e01);
    float2v den = e01 * e23;
    float2v r = { __builtin_amdgcn_rcpf(den.x), __builtin_amdgcn_rcpf(den.y) };
    acc = __builtin_elementwise_fma(num, r, acc);
}

// One 4-h x 4-b x 4-v quad step on preloaded em registers.
__device__ __forceinline__ void quad_step(
    float4v m0, float4v m1, float4v m2, float4v m3,
    float4v ea0, float4v ea1, float4v ea2, float4v ea3,
    float2v c0, float2v c1, float2v c2, float2v c3,
    float2v (&accL)[4], float2v (&accH)[4])
{
    const float2v m0L = lo2(m0), m0H = hi2(m0);
    const float2v m1L = lo2(m1), m1H = hi2(m1);
    const float2v m2L = lo2(m2), m2H = hi2(m2);
    const float2v m3L = lo2(m3), m3H = hi2(m3);
    #pragma unroll
    for (int i = 0; i < 4; i++) {
        const float2v a0 = { ea0[i], ea0[i] };
        const float2v a1 = { ea1[i], ea1[i] };
        const float2v a2 = { ea2[i], ea2[i] };
        const float2v a3 = { ea3[i], ea3[i] };
        rat4(m0L, m1L, m2L, m3L, a0, a1, a2, a3, c0, c1, c2, c3, accL[i]);
        rat4(m0H, m1H, m2H, m3H, a0, a1, a2, a3, c0, c1, c2, c3, accH[i]);
    }
}

// partial[z][b][v] = sum_{h in 64-chunk z} [ w2[h] + c_h / d_h ],
//   c = -2*w2, d = 1 + Ea[h][b]*Em[h][v]    (w2*tanh(x) = w2 - 2*w2/(1+e^{2x}))
// Round 7: explicit software pipeline. Round-4 counters (pair 41.8 us,
// VALUBusy 34%, 1 wave/SIMD) decompose to ~2.1K stall-cycles per q-iter --
// dependent ds_read latency on the critical path. Phases are now
// load/compute separated: emA(q) preloaded; per q issue emB(q) loads ->
// compute quadA(emA) -> issue emA(q+1) -> compute quadB(emB). Every LDS
// read has ~256 cycles of independent rat4 VALU to hide under. 64-h blocks
// staged once (51 KB LDS), grid (16,4,8) = 2 blocks/CU = 8 waves/CU.
__global__ __launch_bounds__(256, 4) void pair_kernel(
    const float* __restrict__ EA, const float* __restrict__ EM,
    const float* __restrict__ w2, float* __restrict__ partial)
{
    __shared__ float sEA[64][68];    // [h][b], 64 cols used
    __shared__ float sEM[64][132];   // [h][v], 128 cols used
    __shared__ float4v sC4[16];      // -2*w2 quads for the 64-h chunk
    const int t  = threadIdx.x;
    const int v0 = blockIdx.x * 128;
    const int b0 = blockIdx.y * 64;
    const int h0 = blockIdx.z * 64;
    const int tx = t & 15;   // quad A: v = v0 + tx*4 + j ; quad B: +64
    const int ty = t >> 4;   // b = b0 + ty*4 + i

    if (t < 16) {
        float4v wvq = *(const float4v*)(w2 + h0 + 4 * t);
        sC4[t] = -2.0f * wvq;
    }

    float2v accAL[4], accAH[4], accBL[4], accBH[4];
    #pragma unroll
    for (int i = 0; i < 4; i++) {
        accAL[i] = (float2v){0.f, 0.f};  accAH[i] = (float2v){0.f, 0.f};
        accBL[i] = (float2v){0.f, 0.f};  accBH[i] = (float2v){0.f, 0.f};
    }

    // ---- stage the block's 64-h chunk (once) ----
    {
        const int rS = t >> 2;            // row 0..63
        const int cq = t & 3;
        const float* pa = EA + (size_t)(h0 + rS) * 256 + b0 + cq * 16;
        #pragma unroll
        for (int i = 0; i < 4; i++) {
            float4v v = *(const float4v*)(pa + 4 * i);
            *(float4v*)&sEA[rS][cq * 16 + 4 * i] = v;
        }
        const float* pm = EM + (size_t)(h0 + rS) * 2048 + v0 + cq * 32;
        #pragma unroll
        for (int i = 0; i < 8; i++) {
            float4v v = *(const float4v*)(pm + 4 * i);
            *(float4v*)&sEM[rS][cq * 32 + 4 * i] = v;
        }
    }
    __syncthreads();

    const int cxA = tx * 4;
    const int cxB = 64 + tx * 4;

    // preload emA(q=0)
    float4v mA0 = *(const float4v*)&sEM[0][cxA];
    float4v mA1 = *(const float4v*)&sEM[1][cxA];
    float4v mA2 = *(const float4v*)&sEM[2][cxA];
    float4v mA3 = *(const float4v*)&sEM[3][cxA];

    #pragma unroll 4
    for (int q = 0; q < 16; q++) {          // 4 h per iteration
        const int hq = 4 * q;
        // issue quad-B em loads (hide under quadA compute)
        float4v mB0 = *(const float4v*)&sEM[hq    ][cxB];
        float4v mB1 = *(const float4v*)&sEM[hq + 1][cxB];
        float4v mB2 = *(const float4v*)&sEM[hq + 2][cxB];
        float4v mB3 = *(const float4v*)&sEM[hq + 3][cxB];
        // ea / c for this q (broadcast within 16-lane groups)
        const float4v ea0 = *(const float4v*)&sEA[hq    ][ty * 4];
        const float4v ea1 = *(const float4v*)&sEA[hq + 1][ty * 4];
        const float4v ea2 = *(const float4v*)&sEA[hq + 2][ty * 4];
        const float4v ea3 = *(const float4v*)&sEA[hq + 3][ty * 4];
        const float4v c = sC4[q];
        const float2v c0 = { c.x, c.x };
        const float2v c1 = { c.y, c.y };
        const float2v c2 = { c.z, c.z };
        const float2v c3 = { c.w, c.w };

        // compute quad A on preloaded emA(q)
        quad_step(mA0, mA1, mA2, mA3, ea0, ea1, ea2, ea3,
                  c0, c1, c2, c3, accAL, accAH);

        // issue emA(q+1) loads (hide under quadB compute); row wraps
        // harmlessly on the last iteration (value unused).
        const int hn = (hq + 4) & 63;
        float4v nA0 = *(const float4v*)&sEM[hn    ][cxA];
        float4v nA1 = *(const float4v*)&sEM[hn + 1][cxA];
        float4v nA2 = *(const float4v*)&sEM[hn + 2][cxA];
        float4v nA3 = *(const float4v*)&sEM[hn + 3][cxA];

        // compute quad B on emB(q)
        quad_step(mB0, mB1, mB2, mB3, ea0, ea1, ea2, ea3,
                  c0, c1, c2, c3, accBL, accBH);

        mA0 = nA0; mA1 = nA1; mA2 = nA2; mA3 = nA3;
    }

    // chunk's sum(w2) from sC4 (sC4 = -2*w2)
    float4v w2q = sC4[0];
    #pragma unroll
    for (int k = 1; k < 16; k++) w2q += sC4[k];
    const float w2s = -0.5f * (w2q.x + w2q.y + w2q.z + w2q.w);

    const size_t pb = (size_t)blockIdx.z * (256 * 2048);
    #pragma unroll
    for (int i = 0; i < 4; i++) {
        const size_t row = pb + (size_t)(b0 + ty * 4 + i) * 2048 + v0 + tx * 4;
        float4v oA = { accAL[i].x + w2s, accAL[i].y + w2s,
                       accAH[i].x + w2s, accAH[i].y + w2s };
        float4v oB = { accBL[i].x + w2s, accBL[i].y + w2s,
                       accBH[i].x + w2s, accBH[i].y + w2s };
        *(float4v*)&partial[row] = oA;
        *(float4v*)&partial[row + 64] = oB;
    }
}

__global__ __launch_bounds__(256) void reduce_kernel(
    const float* __restrict__ partial, const float* __restrict__ b2,
    float* __restrict__ out)
{
    const int i = (blockIdx.x * 256 + threadIdx.x) * 4;
    const float bb = b2[0];
    float4v s = *(const float4v*)&partial[i];
    #pragma unroll
    for (int z = 1; z < 8; z++)
        s += *(const float4v*)&partial[(size_t)z * 524288 + i];
    float4v o = s + bb;
    *(float4v*)&out[i] = o;
}

extern "C" void kernel_launch(void* const* d_in, const int* in_sizes, int n_in,
                              void* d_out, int out_size, void* d_ws, size_t ws_size,
                              hipStream_t stream)
{
    const float* patient = (const float*)d_in[0]; // 256x1024
    const float* atc4    = (const float*)d_in[1]; // 2048x512
    const float* W1      = (const float*)d_in[2]; // 512x1536
    const float* b1      = (const float*)d_in[3]; // 512
    const float* w2      = (const float*)d_in[4]; // 512
    const float* b2      = (const float*)d_in[5]; // 1
    float* out = (float*)d_out;
    float* ws  = (float*)d_ws;

    // ws layout (floats): EA[512][256], EM[512][2048],
    //                     partial[8][256][2048] => ~21.5 MB
    float* EA      = ws;
    float* EM      = ws + 131072;
    float* partial = ws + 1179648;

    // Both GEMMs in one dispatch (compacted grid, EA tiles first); exp(2x) epilogue
    gemm_exp<<<dim3(36, 8, 1), 256, 0, stream>>>(patient, atc4, W1, b1, EA, EM);
    // score partials: software-pipelined 64-h blocks, 2 blocks/CU
    pair_kernel<<<dim3(16, 4, 8), 256, 0, stream>>>(EA, EM, w2, partial);
    // sum 8 h-chunks + b2
    reduce_kernel<<<512, 256, 0, stream>>>(partial, b2, out);
}

// Round 8
// 110.554 us; speedup vs baseline: 1.0345x; 1.0225x over previous
//
#include <hip/hip_runtime.h>
#include <hip/hip_bf16.h>
#include <math.h>

// Problem constants: B=256, V=2048, PD=1024, MD=512, H=512
typedef __attribute__((ext_vector_type(8))) short short8;
typedef __attribute__((ext_vector_type(4))) float float4v;
typedef __attribute__((ext_vector_type(2))) float float2v;

// SSA-safe half extraction (NO unions -- unions block SROA and spill).
__device__ __forceinline__ float2v lo2(float4v v) {
    return __builtin_shufflevector(v, v, 0, 1);
}
__device__ __forceinline__ float2v hi2(float4v v) {
    return __builtin_shufflevector(v, v, 2, 3);
}

__device__ __forceinline__ int2 cvt2bf16x4(float4v v) {
    union { __hip_bfloat162 h2; int i; } u0, u1;
    u0.h2 = __float22bfloat162_rn(make_float2(v.x, v.y));  // v_cvt_pk_bf16_f32
    u1.h2 = __float22bfloat162_rn(make_float2(v.z, v.w));
    return make_int2(u0.i, u1.i);
}

// Fused dual GEMM + exp epilogue (plain [h][x] layout, contiguous stores).
//  bx 0..3:  EA[h][b] = exp(2*(patient@W1p^T + b1))   M=256,  K=1024
//  bx 4..35: EM[h][v] = exp(2*(atc4@W1m^T))           M=2048, K=512
// NOTE (round-3 lesson): do NOT fuse cross-block reductions with
// __threadfence on this chip -- agent-scope fences flush per-XCD L2 and
// cost ~30 us. Separate dispatches keep workspace traffic L2-hot.
__global__ __launch_bounds__(256, 2) void gemm_exp(
    const float* __restrict__ patient, const float* __restrict__ atc4,
    const float* __restrict__ W1, const float* __restrict__ b1,
    float* __restrict__ EA, float* __restrict__ EM)
{
    const float* A; const float* W; const float* bias; float* T;
    int lda, K, M;
    int bx = blockIdx.x;
    if (bx < 4) {
        A = patient; lda = 1024; K = 1024; M = 256; bias = b1; T = EA; W = W1;
    } else {
        bx -= 4;
        A = atc4;    lda = 512;  K = 512;  M = 2048; bias = nullptr; T = EM; W = W1 + 1024;
    }
    const int ldw = 1536;

    __shared__ short As[64][72];
    __shared__ short Bs[64][72];
    const int t = threadIdx.x;
    const int m0 = bx * 64;
    const int n0 = blockIdx.y * 64;
    const int wave = t >> 6;
    const int lane = t & 63;
    const int wm = (wave & 1) * 32;
    const int wn = (wave >> 1) * 32;
    const int lrow = lane & 15;
    const int quad = lane >> 4;

    float4v acc[2][2];
    #pragma unroll
    for (int i = 0; i < 2; i++)
        #pragma unroll
        for (int j = 0; j < 2; j++)
            acc[i][j] = (float4v){0.f, 0.f, 0.f, 0.f};

    const int sr = t >> 2;        // staging row 0..63
    const int sc = (t & 3) * 16;  // staging col 0,16,32,48

    // preload k-tile 0 into registers
    float4v av[4], wv[4];
    {
        const float* ap = A + (size_t)(m0 + sr) * lda + sc;
        const float* wp = W + (size_t)(n0 + sr) * ldw + sc;
        #pragma unroll
        for (int ii = 0; ii < 4; ii++) {
            av[ii] = *(const float4v*)(ap + ii * 4);
            wv[ii] = *(const float4v*)(wp + ii * 4);
        }
    }

    for (int k0 = 0; k0 < K; k0 += 64) {
        #pragma unroll
        for (int ii = 0; ii < 4; ii++) {
            *(int2*)&As[sr][sc + ii * 4] = cvt2bf16x4(av[ii]);
            *(int2*)&Bs[sr][sc + ii * 4] = cvt2bf16x4(wv[ii]);
        }
        __syncthreads();
        if (k0 + 64 < K) {   // prefetch next k-tile; latency hides under MFMA
            const float* ap = A + (size_t)(m0 + sr) * lda + (k0 + 64 + sc);
            const float* wp = W + (size_t)(n0 + sr) * ldw + (k0 + 64 + sc);
            #pragma unroll
            for (int ii = 0; ii < 4; ii++) {
                av[ii] = *(const float4v*)(ap + ii * 4);
                wv[ii] = *(const float4v*)(wp + ii * 4);
            }
        }
        #pragma unroll
        for (int kk = 0; kk < 64; kk += 32) {
            short8 af[2], bfr[2];
            #pragma unroll
            for (int i = 0; i < 2; i++)
                af[i] = *(const short8*)&As[wm + i * 16 + lrow][kk + quad * 8];
            #pragma unroll
            for (int j = 0; j < 2; j++)
                bfr[j] = *(const short8*)&Bs[wn + j * 16 + lrow][kk + quad * 8];
            #pragma unroll
            for (int i = 0; i < 2; i++)
                #pragma unroll
                for (int j = 0; j < 2; j++)
                    acc[i][j] = __builtin_amdgcn_mfma_f32_16x16x32_bf16(
                        af[i], bfr[j], acc[i][j], 0, 0, 0);
        }
        __syncthreads();
    }

    // D layout (verified m89/m91): col(n)=lane&15, row(m)=quad*4+reg
    #pragma unroll
    for (int i = 0; i < 2; i++) {
        #pragma unroll
        for (int j = 0; j < 2; j++) {
            const int n  = n0 + wn + j * 16 + lrow;
            const int mb = m0 + wm + i * 16 + quad * 4;
            const float bn = bias ? bias[n] : 0.0f;
            float4v ev;
            #pragma unroll
            for (int r = 0; r < 4; r++)
                ev[r] = __expf(2.0f * (acc[i][j][r] + bn));
            *(float4v*)&T[(size_t)n * M + mb] = ev;
        }
    }
}

// 4-h rational block: acc += sum_{k=0..3} c_k / d_k, d_k = 1 + em_k*a_k.
//   (n01*e23 + n23*e01)/(e01*e23); all d >= 1 so no cancellation.
__device__ __forceinline__ void rat4(
    float2v em0, float2v em1, float2v em2, float2v em3,
    float2v a0, float2v a1, float2v a2, float2v a3,
    float2v c0, float2v c1, float2v c2, float2v c3,
    float2v& acc)
{
    const float2v one2 = {1.f, 1.f};
    float2v d0 = __builtin_elementwise_fma(em0, a0, one2);
    float2v d1 = __builtin_elementwise_fma(em1, a1, one2);
    float2v d2 = __builtin_elementwise_fma(em2, a2, one2);
    float2v d3 = __builtin_elementwise_fma(em3, a3, one2);
    float2v e01 = d0 * d1;
    float2v e23 = d2 * d3;
    float2v n01 = __builtin_elementwise_fma(d1, c0, d0 * c1);
    float2v n23 = __builtin_elementwise_fma(d3, c2, d2 * c3);
    float2v num = __builtin_elementwise_fma(n01, e23, n23 * e01);
    float2v den = e01 * e23;
    float2v r = { __builtin_amdgcn_rcpf(den.x), __builtin_amdgcn_rcpf(den.y) };
    acc = __builtin_elementwise_fma(num, r, acc);
}

// partial[z][b][v] = sum_{h in 64-chunk z} [ w2[h] + c_h / d_h ],
//   c = -2*w2, d = 1 + Ea[h][b]*Em[h][v]    (w2*tanh(x) = w2 - 2*w2/(1+e^{2x}))
// Round 8: MINIMAL PRESSURE variant. R4-R7 showed pair invariant at
// ~38-42 us across occupancy 1-8 blk/CU, staging, and pipelining; R4's
// VALUBusy(34%) x dur = 14 us VALU-issue, rest stall -- the signature of
// the scratch/remat pathology this file's header documents (allocator
// pinned at 64-76 VGPR vs ~100+ live set of the 8v x 4b tile). Fix the
// PRESSURE, not the schedule: 4v x 4b per thread (16 acc floats),
// unroll 1 (one 4-h slab live at a time, ~50 regs), single barrier.
// Tile 64v x 64b x 64h, grid (32,4,8) = 1024 blocks = 4 blocks/CU.
__global__ __launch_bounds__(256, 4) void pair_kernel(
    const float* __restrict__ EA, const float* __restrict__ EM,
    const float* __restrict__ w2, float* __restrict__ partial)
{
    __shared__ float sEA[64][68];    // [h][b], 64 cols used
    __shared__ float sEM[64][68];    // [h][v], 64 cols used
    __shared__ float4v sC4[16];      // -2*w2 quads for the 64-h chunk
    const int t  = threadIdx.x;
    const int v0 = blockIdx.x * 64;
    const int b0 = blockIdx.y * 64;
    const int h0 = blockIdx.z * 64;
    const int tx = t & 15;   // v = v0 + tx*4 + j
    const int ty = t >> 4;   // b = b0 + ty*4 + i

    if (t < 16) {
        float4v wvq = *(const float4v*)(w2 + h0 + 4 * t);
        sC4[t] = -2.0f * wvq;
    }

    float2v accL[4], accH[4];        // [b][low/high half of v-quad]
    #pragma unroll
    for (int i = 0; i < 4; i++) {
        accL[i] = (float2v){0.f, 0.f};
        accH[i] = (float2v){0.f, 0.f};
    }

    // ---- stage the block's 64-h chunk (once): 4 threads/row, 4 float4 each
    {
        const int rS = t >> 2;            // row 0..63
        const int c0i = (t & 3) * 16;     // col 0,16,32,48
        const float* pa = EA + (size_t)(h0 + rS) * 256 + b0 + c0i;
        const float* pm = EM + (size_t)(h0 + rS) * 2048 + v0 + c0i;
        #pragma unroll
        for (int i = 0; i < 4; i++) {
            float4v va = *(const float4v*)(pa + 4 * i);
            float4v vm = *(const float4v*)(pm + 4 * i);
            *(float4v*)&sEA[rS][c0i + 4 * i] = va;
            *(float4v*)&sEM[rS][c0i + 4 * i] = vm;
        }
    }
    __syncthreads();

    #pragma unroll 1
    for (int q = 0; q < 16; q++) {       // 4 h per iteration, minimal live set
        const int hq = 4 * q;
        const float4v m0 = *(const float4v*)&sEM[hq    ][tx * 4];
        const float4v m1 = *(const float4v*)&sEM[hq + 1][tx * 4];
        const float4v m2 = *(const float4v*)&sEM[hq + 2][tx * 4];
        const float4v m3 = *(const float4v*)&sEM[hq + 3][tx * 4];
        const float4v ea0 = *(const float4v*)&sEA[hq    ][ty * 4];
        const float4v ea1 = *(const float4v*)&sEA[hq + 1][ty * 4];
        const float4v ea2 = *(const float4v*)&sEA[hq + 2][ty * 4];
        const float4v ea3 = *(const float4v*)&sEA[hq + 3][ty * 4];
        const float4v c = sC4[q];
        const float2v c0 = { c.x, c.x };
        const float2v c1 = { c.y, c.y };
        const float2v c2 = { c.z, c.z };
        const float2v c3 = { c.w, c.w };
        const float2v m0L = lo2(m0), m0H = hi2(m0);
        const float2v m1L = lo2(m1), m1H = hi2(m1);
        const float2v m2L = lo2(m2), m2H = hi2(m2);
        const float2v m3L = lo2(m3), m3H = hi2(m3);
        #pragma unroll
        for (int i = 0; i < 4; i++) {    // b within the thread's 4
            const float2v a0 = { ea0[i], ea0[i] };
            const float2v a1 = { ea1[i], ea1[i] };
            const float2v a2 = { ea2[i], ea2[i] };
            const float2v a3 = { ea3[i], ea3[i] };
            rat4(m0L, m1L, m2L, m3L, a0, a1, a2, a3, c0, c1, c2, c3, accL[i]);
            rat4(m0H, m1H, m2H, m3H, a0, a1, a2, a3, c0, c1, c2, c3, accH[i]);
        }
    }

    // chunk's sum(w2) from sC4 (sC4 = -2*w2)
    float4v w2q = sC4[0];
    #pragma unroll
    for (int k = 1; k < 16; k++) w2q += sC4[k];
    const float w2s = -0.5f * (w2q.x + w2q.y + w2q.z + w2q.w);

    const size_t pb = (size_t)blockIdx.z * (256 * 2048);
    #pragma unroll
    for (int i = 0; i < 4; i++) {
        const size_t row = pb + (size_t)(b0 + ty * 4 + i) * 2048 + v0 + tx * 4;
        float4v o = { accL[i].x + w2s, accL[i].y + w2s,
                      accH[i].x + w2s, accH[i].y + w2s };
        *(float4v*)&partial[row] = o;
    }
}

__global__ __launch_bounds__(256) void reduce_kernel(
    const float* __restrict__ partial, const float* __restrict__ b2,
    float* __restrict__ out)
{
    const int i = (blockIdx.x * 256 + threadIdx.x) * 4;
    const float bb = b2[0];
    float4v s = *(const float4v*)&partial[i];
    #pragma unroll
    for (int z = 1; z < 8; z++)
        s += *(const float4v*)&partial[(size_t)z * 524288 + i];
    float4v o = s + bb;
    *(float4v*)&out[i] = o;
}

extern "C" void kernel_launch(void* const* d_in, const int* in_sizes, int n_in,
                              void* d_out, int out_size, void* d_ws, size_t ws_size,
                              hipStream_t stream)
{
    const float* patient = (const float*)d_in[0]; // 256x1024
    const float* atc4    = (const float*)d_in[1]; // 2048x512
    const float* W1      = (const float*)d_in[2]; // 512x1536
    const float* b1      = (const float*)d_in[3]; // 512
    const float* w2      = (const float*)d_in[4]; // 512
    const float* b2      = (const float*)d_in[5]; // 1
    float* out = (float*)d_out;
    float* ws  = (float*)d_ws;

    // ws layout (floats): EA[512][256], EM[512][2048],
    //                     partial[8][256][2048] => ~21.5 MB
    float* EA      = ws;
    float* EM      = ws + 131072;
    float* partial = ws + 1179648;

    // Both GEMMs in one dispatch (compacted grid, EA tiles first); exp(2x) epilogue
    gemm_exp<<<dim3(36, 8, 1), 256, 0, stream>>>(patient, atc4, W1, b1, EA, EM);
    // score partials: minimal-pressure 4v x 4b threads, 64h blocks, 4 blk/CU
    pair_kernel<<<dim3(32, 4, 8), 256, 0, stream>>>(EA, EM, w2, partial);
    // sum 8 h-chunks + b2
    reduce_kernel<<<512, 256, 0, stream>>>(partial, b2, out);
}